// Round 7
// baseline (117.626 us; speedup 1.0000x reference)
//
#include <hip/hip_runtime.h>

typedef __bf16 bf16x8 __attribute__((ext_vector_type(8)));
typedef float f32x4 __attribute__((ext_vector_type(4)));

#define TWO_LOG2E 2.88539008177792681f   // 2*log2(e): exp(2x) = exp2(x*TWO_LOG2E)

#define GLOADLDS16(g, l) __builtin_amdgcn_global_load_lds(                     \
    (const __attribute__((address_space(1))) void*)(g),                        \
    (__attribute__((address_space(3))) void*)(l), 16, 0, 0)

__device__ __forceinline__ unsigned f2bf(float f) {
    unsigned u = __float_as_uint(f);
    return (u + 0x7FFFu + ((u >> 16) & 1u)) >> 16;   // RNE
}

// ---------------- kernel 1: row-normalize z=[z1;z2] -> bf16 zn[8192][256] ---------------
__global__ void __launch_bounds__(256) normalize_kernel(
    const float* __restrict__ z1, const float* __restrict__ z2,
    unsigned short* __restrict__ zn, float* __restrict__ S, float* __restrict__ out)
{
    if (blockIdx.x < 32) S[(blockIdx.x << 8) + threadIdx.x] = 0.f;
    if (blockIdx.x == 32 && threadIdx.x == 0) out[0] = 0.f;

    const int wave = threadIdx.x >> 6, lane = threadIdx.x & 63;
    const int row = (blockIdx.x << 2) + wave;               // 2048 blocks * 4 rows
    const float* src = (row < 4096) ? (z1 + row * 256) : (z2 + (row - 4096) * 256);
    float4 v = ((const float4*)src)[lane];                  // 64 lanes * 4 = 256
    float ss = v.x * v.x + v.y * v.y + v.z * v.z + v.w * v.w;
#pragma unroll
    for (int m = 32; m > 0; m >>= 1) ss += __shfl_xor(ss, m, 64);
    float sc = 1.0f / fmaxf(sqrtf(ss), 1e-8f);
    uint2 w;
    w.x = f2bf(v.x * sc) | (f2bf(v.y * sc) << 16);
    w.y = f2bf(v.z * sc) | (f2bf(v.w * sc) << 16);
    *(uint2*)(zn + row * 256 + (lane << 2)) = w;
}

// ---------------- kernel 2: symmetric triangle, two specialized paths -------------------
// R6 post-mortem fixes: (1) col-atomic storm (2048 global atomics/block -> 256 via LDS
// colpart cross-wave reduction); (2) dual-diag imbalance (64 lockstep intervals -> 9
// uniform wave-autonomous chunk-columns per wave, no barriers, B direct from L2).
//
// Jobs 0..495: off-diag tile (ti<tj), R4-proven lockstep skeleton (parity staging,
//   ring-4, counted vmcnt(1), raw s_barrier; NEVER __syncthreads mid-loop). Per-chunk
//   epilogue: rs += exp (rows), cs q-reduced -> plain store colpart[wv][32cc+16ct+n16].
//   After the tail (vmcnt fully drained -> __syncthreads is SAFE here), threads 0..255
//   sum colpart over 8 waves and do ONE atomicAdd per column. 320 atomics/block total.
// Jobs 496..511: dual-diagonal block, tiles (2j,2j+1). No LDS, no barriers: a diag
//   tile's B-panel IS its A-strip (L2-hot), so B-frags load direct from zn with the
//   same per-lane addressing as the proven a[] loads. Wave w covers tile0 rows 32w,
//   chunks cc>=w (8-w cols) and tile1 rows 32(7-w), chunks cc>=7-w (w+1 cols): 9
//   chunk-columns per wave, uniform. cc==w' chunk computes both orderings of each pair
//   -> row-path only; cc>w' chunks scatter rows (rs) AND mirror cols (atomicAdd, only
//   7 chunks/wave * 16 blocks - negligible). Self-sim included; finish subtracts it.
__global__ void __launch_bounds__(512, 4) simexp_kernel(
    const unsigned short* __restrict__ zn, float* __restrict__ S)
{
    __shared__ __align__(16) unsigned short Bs[4][2048];    // 4 x 4KB ring (off-diag)
    __shared__ float colpart[8][256];                       // per-wave col partials

    const int tid = threadIdx.x;
    const int wv = tid >> 6, lane = tid & 63;
    const int q = lane >> 4, n16 = lane & 15;
    const int g = wv >> 2, wl = wv & 3;         // staging group / quarter within group
    const int job = blockIdx.x;                 // 0..511

    if (job >= 496) {                           // ---------- dual-diagonal path ----------
        const int t0 = (job - 496) << 1;
        for (int rep = 0; rep < 2; ++rep) {
            const int t = t0 + rep;
            const int wp = rep ? (7 - wv) : wv; // row-wave remap balances chunk counts
            const int colTile = t << 8;
            const int rowW = colTile + (wp << 5);

            bf16x8 a[2][8];
#pragma unroll
            for (int rt = 0; rt < 2; ++rt)
#pragma unroll
                for (int ks = 0; ks < 8; ++ks)
                    a[rt][ks] = *(const bf16x8*)(zn + ((rowW + (rt << 4) + n16) << 8)
                                                    + (ks << 5) + (q << 3));
            float rs[2][4];
#pragma unroll
            for (int i = 0; i < 2; ++i)
#pragma unroll
                for (int j = 0; j < 4; ++j) rs[i][j] = 0.f;

            for (int cc = wp; cc < 8; ++cc) {   // wave-autonomous: no barriers
                f32x4 acc[2][2];
#pragma unroll
                for (int rt = 0; rt < 2; ++rt)
#pragma unroll
                    for (int ct = 0; ct < 2; ++ct)
                        acc[rt][ct] = (f32x4){0.f, 0.f, 0.f, 0.f};
#pragma unroll
                for (int kc = 0; kc < 4; ++kc)
#pragma unroll
                    for (int ks = 0; ks < 2; ++ks) {
                        bf16x8 bf[2];
#pragma unroll
                        for (int ct = 0; ct < 2; ++ct) {
                            int col = colTile + (cc << 5) + (ct << 4) + n16;
                            bf[ct] = *(const bf16x8*)(zn + (col << 8)
                                        + (((kc << 1) + ks) << 5) + (q << 3));
                        }
#pragma unroll
                        for (int rt = 0; rt < 2; ++rt)
#pragma unroll
                            for (int ct = 0; ct < 2; ++ct)
                                acc[rt][ct] = __builtin_amdgcn_mfma_f32_16x16x32_bf16(
                                    a[rt][(kc << 1) + ks], bf[ct], acc[rt][ct], 0, 0, 0);
                    }
                float cs[2] = {0.f, 0.f};
#pragma unroll
                for (int rt = 0; rt < 2; ++rt)
#pragma unroll
                    for (int ct = 0; ct < 2; ++ct)
#pragma unroll
                        for (int r = 0; r < 4; ++r) {
                            float e = __builtin_amdgcn_exp2f(acc[rt][ct][r] * TWO_LOG2E);
                            rs[rt][r] += e;
                            cs[ct] += e;
                        }
                if (cc > wp) {                  // mirror scatter (cc==wp covers both)
#pragma unroll
                    for (int ct = 0; ct < 2; ++ct) {
                        float s = cs[ct];
                        s += __shfl_xor(s, 16, 64);
                        s += __shfl_xor(s, 32, 64);
                        if (lane < 16)
                            atomicAdd(&S[colTile + (cc << 5) + (ct << 4) + n16], s);
                    }
                }
            }
#pragma unroll
            for (int rt = 0; rt < 2; ++rt)
#pragma unroll
                for (int r = 0; r < 4; ++r) {
                    float s = rs[rt][r];
                    s += __shfl_xor(s, 1, 64);
                    s += __shfl_xor(s, 2, 64);
                    s += __shfl_xor(s, 4, 64);
                    s += __shfl_xor(s, 8, 64);
                    if (n16 == 0) atomicAdd(&S[rowW + (rt << 4) + (q << 2) + r], s);
                }
        }
        return;
    }

    // ------------------------------- off-diagonal path ---------------------------------
    int ti, tj;
    {
        int t = 0, rem = job;
        while (rem >= 31 - t) { rem -= 31 - t; ++t; }   // uniform scan, <=31 iters
        ti = t; tj = t + 1 + rem;
    }
    const int colTile = tj << 8;
    const int rowW = (ti << 8) + (wv << 5);     // this wave's 32 rows

    bf16x8 a[2][8];
#pragma unroll
    for (int rt = 0; rt < 2; ++rt)
#pragma unroll
        for (int ks = 0; ks < 8; ++ks)
            a[rt][ks] = *(const bf16x8*)(zn + ((rowW + (rt << 4) + n16) << 8)
                                            + (ks << 5) + (q << 3));

    auto stage = [&](int m) {                   // 128B-contiguous rows (R3 lesson)
        const int colBase = colTile + ((m >> 2) << 5);
        const int koff = (m & 3) << 6;
        unsigned short* base = &Bs[m & 3][0];
        int s = (wl << 6) + lane;               // 16B slot 0..255
        int c = s >> 3, d = s & 7;
        int k8 = d ^ (c & 7);                   // XOR swizzle (conflict-free b128 reads)
        GLOADLDS16(zn + ((colBase + c) << 8) + koff + (k8 << 3), base + (s << 3));
    };

    float rs[2][4];
#pragma unroll
    for (int i = 0; i < 2; ++i)
#pragma unroll
        for (int j = 0; j < 4; ++j) rs[i][j] = 0.f;

    f32x4 acc[2][2];
    auto consume = [&](int kc) {
        const unsigned short* bb = &Bs[kc & 3][0];
#pragma unroll
        for (int ks = 0; ks < 2; ++ks) {
            bf16x8 bf[2];
#pragma unroll
            for (int ct = 0; ct < 2; ++ct) {
                int c  = (ct << 4) + n16;
                int k8 = ((ks << 2) + q) ^ (c & 7);
                bf[ct] = *(const bf16x8*)(bb + (((c << 3) + k8) << 3));
            }
#pragma unroll
            for (int rt = 0; rt < 2; ++rt)
#pragma unroll
                for (int ct = 0; ct < 2; ++ct)
                    acc[rt][ct] = __builtin_amdgcn_mfma_f32_16x16x32_bf16(
                        a[rt][(kc << 1) + ks], bf[ct], acc[rt][ct], 0, 0, 0);
        }
    };
    auto zacc = [&]() {
#pragma unroll
        for (int rt = 0; rt < 2; ++rt)
#pragma unroll
            for (int ct = 0; ct < 2; ++ct) acc[rt][ct] = (f32x4){0.f, 0.f, 0.f, 0.f};
    };
    auto epiC = [&](int cc) {                   // rows -> rs; cols -> colpart (LDS)
        float cs[2] = {0.f, 0.f};
#pragma unroll
        for (int rt = 0; rt < 2; ++rt)
#pragma unroll
            for (int ct = 0; ct < 2; ++ct)
#pragma unroll
                for (int r = 0; r < 4; ++r) {
                    float e = __builtin_amdgcn_exp2f(acc[rt][ct][r] * TWO_LOG2E);
                    rs[rt][r] += e;
                    cs[ct] += e;
                }
#pragma unroll
        for (int ct = 0; ct < 2; ++ct) {
            float s = cs[ct];
            s += __shfl_xor(s, 16, 64);         // reduce over q
            s += __shfl_xor(s, 32, 64);
            if (lane < 16) colpart[wv][(cc << 5) + (ct << 4) + n16] = s;
        }
    };

    if (g == 0) stage(0); else stage(1);        // prologue, parity-consistent

    for (int cc = 0; cc < 7; ++cc) {            // intervals m=cc*4+kc, m=0..27
        zacc();
#pragma unroll
        for (int kc = 0; kc < 4; ++kc) {
            if ((kc & 1) == g) {                // wave-uniform branch
                stage((cc << 2) + kc + 2);
                asm volatile("s_waitcnt vmcnt(1)" ::: "memory");  // own chunk-m done
            }
            __builtin_amdgcn_s_barrier();
            asm volatile("" ::: "memory");      // keep ds_reads below the barrier
            consume(kc);
        }
        epiC(cc);
    }
    // peeled tail cc=7: chunks 28..31 (stage 30 by g0, 31 by g1, then drain)
    zacc();
    if (g == 0) { stage(30); asm volatile("s_waitcnt vmcnt(1)" ::: "memory"); }
    __builtin_amdgcn_s_barrier();
    asm volatile("" ::: "memory");
    consume(0);
    if (g == 1) { stage(31); asm volatile("s_waitcnt vmcnt(1)" ::: "memory"); }
    __builtin_amdgcn_s_barrier();
    asm volatile("" ::: "memory");
    consume(1);
    if (g == 0) { asm volatile("s_waitcnt vmcnt(0)" ::: "memory"); }
    __builtin_amdgcn_s_barrier();
    asm volatile("" ::: "memory");
    consume(2);
    if (g == 1) { asm volatile("s_waitcnt vmcnt(0)" ::: "memory"); }
    __builtin_amdgcn_s_barrier();
    asm volatile("" ::: "memory");
    consume(3);
    epiC(7);

    // row flush (C/D layout: col=n16, row=q*4+r)
#pragma unroll
    for (int rt = 0; rt < 2; ++rt)
#pragma unroll
        for (int r = 0; r < 4; ++r) {
            float s = rs[rt][r];
            s += __shfl_xor(s, 1, 64);
            s += __shfl_xor(s, 2, 64);
            s += __shfl_xor(s, 4, 64);
            s += __shfl_xor(s, 8, 64);
            if (n16 == 0) atomicAdd(&S[rowW + (rt << 4) + (q << 2) + r], s);
        }

    // cross-wave col reduction: ONE atomic per column (vmcnt fully drained above ->
    // __syncthreads is safe at this point; it also publishes colpart LDS writes)
    __syncthreads();
    if (tid < 256) {
        float s = 0.f;
#pragma unroll
        for (int w = 0; w < 8; ++w) s += colpart[w][tid];
        atomicAdd(&S[colTile + tid], s);
    }
}

// ---------------- kernel 3: loss = mean( log(S_i - e^{sim_ii}) - sim_{i,target} ) -------
__global__ void __launch_bounds__(256) finish_kernel(
    const unsigned short* __restrict__ zn, const float* __restrict__ S,
    float* __restrict__ out)
{
    __shared__ float vals[16];
    const int tid = threadIdx.x, lane = tid & 63, wave = tid >> 6;
    const int q = lane >> 4, n16 = lane & 15;
    const int rib = (wave << 2) + q;                // 0..15 rows per block
    const int row = (blockIdx.x << 4) + rib;        // 512 blocks * 16 rows
    const int tar = (row + 4096) & 8191;

    float drr = 0.f, drt = 0.f;
#pragma unroll
    for (int i = 0; i < 4; ++i) {
        int k = (i << 6) + (n16 << 2);
        uint2 ur = *(const uint2*)(zn + (row << 8) + k);
        uint2 ut = *(const uint2*)(zn + (tar << 8) + k);
        float a0 = __uint_as_float(ur.x << 16),  a1 = __uint_as_float(ur.x & 0xFFFF0000u);
        float a2 = __uint_as_float(ur.y << 16),  a3 = __uint_as_float(ur.y & 0xFFFF0000u);
        float b0 = __uint_as_float(ut.x << 16),  b1 = __uint_as_float(ut.x & 0xFFFF0000u);
        float b2 = __uint_as_float(ut.y << 16),  b3 = __uint_as_float(ut.y & 0xFFFF0000u);
        drr += a0 * a0 + a1 * a1 + a2 * a2 + a3 * a3;
        drt += a0 * b0 + a1 * b1 + a2 * b2 + a3 * b3;
    }
#pragma unroll
    for (int m = 1; m <= 8; m <<= 1) {
        drr += __shfl_xor(drr, m, 64);
        drt += __shfl_xor(drt, m, 64);
    }
    if (n16 == 0) {
        float Sv = S[row] - __builtin_amdgcn_exp2f(drr * TWO_LOG2E);  // remove diagonal
        vals[rib] = 0.693147180559945f * __builtin_amdgcn_logf(Sv) - 2.0f * drt;
    }
    __syncthreads();
    if (tid == 0) {
        float s = 0.f;
#pragma unroll
        for (int i = 0; i < 16; ++i) s += vals[i];
        atomicAdd(out, s * (1.0f / 8192.0f));
    }
}

extern "C" void kernel_launch(void* const* d_in, const int* in_sizes, int n_in,
                              void* d_out, int out_size, void* d_ws, size_t ws_size,
                              hipStream_t stream)
{
    const float* z1 = (const float*)d_in[0];
    const float* z2 = (const float*)d_in[1];
    unsigned short* zn = (unsigned short*)d_ws;                              // 4 MB
    float* S = (float*)((char*)d_ws + 8192 * 256 * sizeof(unsigned short));  // 32 KB
    float* out = (float*)d_out;

    normalize_kernel<<<2048, 256, 0, stream>>>(z1, z2, zn, S, out);
    simexp_kernel<<<512, 512, 0, stream>>>(zn, S);
    finish_kernel<<<512, 256, 0, stream>>>(zn, S, out);
}

// Round 8
// 100.491 us; speedup vs baseline: 1.1705x; 1.1705x over previous
//
#include <hip/hip_runtime.h>

typedef __bf16 bf16x8 __attribute__((ext_vector_type(8)));
typedef float f32x4 __attribute__((ext_vector_type(4)));

#define TWO_LOG2E 2.88539008177792681f   // 2*log2(e): exp(2x) = exp2(x*TWO_LOG2E)

#define GLOADLDS16(g, l) __builtin_amdgcn_global_load_lds(                     \
    (const __attribute__((address_space(1))) void*)(g),                        \
    (__attribute__((address_space(3))) void*)(l), 16, 0, 0)

__device__ __forceinline__ unsigned f2bf(float f) {
    unsigned u = __float_as_uint(f);
    return (u + 0x7FFFu + ((u >> 16) & 1u)) >> 16;   // RNE
}

// ---------------- kernel 1: row-normalize z=[z1;z2] -> bf16 zn[8192][256] ---------------
__global__ void __launch_bounds__(256) normalize_kernel(
    const float* __restrict__ z1, const float* __restrict__ z2,
    unsigned short* __restrict__ zn, float* __restrict__ S, float* __restrict__ out)
{
    if (blockIdx.x < 32) S[(blockIdx.x << 8) + threadIdx.x] = 0.f;
    if (blockIdx.x == 32 && threadIdx.x == 0) out[0] = 0.f;

    const int wave = threadIdx.x >> 6, lane = threadIdx.x & 63;
    const int row = (blockIdx.x << 2) + wave;               // 2048 blocks * 4 rows
    const float* src = (row < 4096) ? (z1 + row * 256) : (z2 + (row - 4096) * 256);
    float4 v = ((const float4*)src)[lane];                  // 64 lanes * 4 = 256
    float ss = v.x * v.x + v.y * v.y + v.z * v.z + v.w * v.w;
#pragma unroll
    for (int m = 32; m > 0; m >>= 1) ss += __shfl_xor(ss, m, 64);
    float sc = 1.0f / fmaxf(sqrtf(ss), 1e-8f);
    uint2 w;
    w.x = f2bf(v.x * sc) | (f2bf(v.y * sc) << 16);
    w.y = f2bf(v.z * sc) | (f2bf(v.w * sc) << 16);
    *(uint2*)(zn + row * 256 + (lane << 2)) = w;
}

// ---------------- kernel 2: symmetric triangle, ONE uniform proven body ----------------
// R7 post-mortem: the dual-diag direct-global B path was the regression (scattered
// 64-transaction loads, 16 straggler blocks set the 52us makespan). R8 unifies: ALL 528
// upper-triangle tiles (496 off-diag + 32 diag) are identical 32-interval lockstep
// blocks using the R4-measured body (0.31us per CU-resident block-interval):
//   parity staging (group g=wv>>2 stages parity-g chunks, 128B-contiguous rows, XOR
//   swizzle), ring-4 depth-2, counted `s_waitcnt vmcnt(1)`, raw s_barrier publish.
//   NEVER __syncthreads mid-loop (drains vmcnt).
// Off-diag (ti<tj): rows -> rs (atomic flush), cols -> colpart LDS, cross-wave reduce,
//   ONE atomic per column (R7-proven, 320 atomics/block).
// Diag (ti==tj): row path ONLY -- a fully computed diag tile contains both orderings
//   of every pair, so row-sums cover it; self-sim included, finish subtracts it.
// Load balance: 528 blocks, 512 co-resident (2/CU), HW backfills the last 16.
__global__ void __launch_bounds__(512, 4) simexp_kernel(
    const unsigned short* __restrict__ zn, float* __restrict__ S)
{
    __shared__ __align__(16) unsigned short Bs[4][2048];    // 4 x 4KB ring
    __shared__ float colpart[8][256];                       // per-wave col partials

    const int tid = threadIdx.x;
    const int wv = tid >> 6, lane = tid & 63;
    const int q = lane >> 4, n16 = lane & 15;
    const int g = wv >> 2, wl = wv & 3;         // staging group / quarter within group
    const int job = blockIdx.x;                 // 0..527

    int ti, tj;
    bool diag;
    if (job >= 496) {                           // diagonal tile
        ti = tj = job - 496;
        diag = true;
    } else {                                    // off-diag tile, ti<tj
        int t = 0, rem = job;
        while (rem >= 31 - t) { rem -= 31 - t; ++t; }   // uniform scan, <=31 iters
        ti = t; tj = t + 1 + rem;
        diag = false;
    }
    const int colTile = tj << 8;
    const int rowW = (ti << 8) + (wv << 5);     // this wave's 32 rows

    // A: 32 rows x K=256 in registers (frag: row=n16, k=q*8 within 32-elem step)
    bf16x8 a[2][8];
#pragma unroll
    for (int rt = 0; rt < 2; ++rt)
#pragma unroll
        for (int ks = 0; ks < 8; ++ks)
            a[rt][ks] = *(const bf16x8*)(zn + ((rowW + (rt << 4) + n16) << 8)
                                            + (ks << 5) + (q << 3));

    auto stage = [&](int m) {                   // 128B-contiguous rows (R3/R7 lesson)
        const int colBase = colTile + ((m >> 2) << 5);
        const int koff = (m & 3) << 6;
        unsigned short* base = &Bs[m & 3][0];
        int s = (wl << 6) + lane;               // 16B slot 0..255
        int c = s >> 3, d = s & 7;              // 8 consecutive lanes per row -> 128B
        int k8 = d ^ (c & 7);                   // XOR swizzle (conflict-free b128 reads)
        GLOADLDS16(zn + ((colBase + c) << 8) + koff + (k8 << 3), base + (s << 3));
    };

    float rs[2][4];
#pragma unroll
    for (int i = 0; i < 2; ++i)
#pragma unroll
        for (int j = 0; j < 4; ++j) rs[i][j] = 0.f;

    f32x4 acc[2][2];
    auto consume = [&](int kc) {                // buffer kc (m&3==kc since m=cc*4+kc)
        const unsigned short* bb = &Bs[kc & 3][0];
#pragma unroll
        for (int ks = 0; ks < 2; ++ks) {
            bf16x8 bf[2];
#pragma unroll
            for (int ct = 0; ct < 2; ++ct) {
                int c  = (ct << 4) + n16;               // col 0..31
                int k8 = ((ks << 2) + q) ^ (c & 7);     // swizzled chunk
                bf[ct] = *(const bf16x8*)(bb + (((c << 3) + k8) << 3));
            }
#pragma unroll
            for (int rt = 0; rt < 2; ++rt)
#pragma unroll
                for (int ct = 0; ct < 2; ++ct)
                    acc[rt][ct] = __builtin_amdgcn_mfma_f32_16x16x32_bf16(
                        a[rt][(kc << 1) + ks], bf[ct], acc[rt][ct], 0, 0, 0);
        }
    };
    auto zacc = [&]() {
#pragma unroll
        for (int rt = 0; rt < 2; ++rt)
#pragma unroll
            for (int ct = 0; ct < 2; ++ct) acc[rt][ct] = (f32x4){0.f, 0.f, 0.f, 0.f};
    };
    auto epiC = [&](int cc) {                   // rows -> rs; cols -> colpart (off-diag)
        float cs[2] = {0.f, 0.f};
#pragma unroll
        for (int rt = 0; rt < 2; ++rt)
#pragma unroll
            for (int ct = 0; ct < 2; ++ct)
#pragma unroll
                for (int r = 0; r < 4; ++r) {
                    float e = __builtin_amdgcn_exp2f(acc[rt][ct][r] * TWO_LOG2E);
                    rs[rt][r] += e;
                    cs[ct] += e;
                }
        if (!diag) {                            // wave-uniform
#pragma unroll
            for (int ct = 0; ct < 2; ++ct) {
                float s = cs[ct];
                s += __shfl_xor(s, 16, 64);     // reduce over q
                s += __shfl_xor(s, 32, 64);
                if (lane < 16) colpart[wv][(cc << 5) + (ct << 4) + n16] = s;
            }
        }
    };

    if (g == 0) stage(0); else stage(1);        // prologue, parity-consistent

    for (int cc = 0; cc < 7; ++cc) {            // intervals m=cc*4+kc, m=0..27
        zacc();
#pragma unroll
        for (int kc = 0; kc < 4; ++kc) {
            if ((kc & 1) == g) {                // wave-uniform branch
                stage((cc << 2) + kc + 2);
                asm volatile("s_waitcnt vmcnt(1)" ::: "memory");  // own chunk-m done
            }
            __builtin_amdgcn_s_barrier();
            asm volatile("" ::: "memory");      // keep ds_reads below the barrier
            consume(kc);
        }
        epiC(cc);
    }
    // peeled tail cc=7: chunks 28..31 (stage 30 by g0, 31 by g1, then drain)
    zacc();
    if (g == 0) { stage(30); asm volatile("s_waitcnt vmcnt(1)" ::: "memory"); }
    __builtin_amdgcn_s_barrier();
    asm volatile("" ::: "memory");
    consume(0);
    if (g == 1) { stage(31); asm volatile("s_waitcnt vmcnt(1)" ::: "memory"); }
    __builtin_amdgcn_s_barrier();
    asm volatile("" ::: "memory");
    consume(1);
    if (g == 0) { asm volatile("s_waitcnt vmcnt(0)" ::: "memory"); }
    __builtin_amdgcn_s_barrier();
    asm volatile("" ::: "memory");
    consume(2);
    if (g == 1) { asm volatile("s_waitcnt vmcnt(0)" ::: "memory"); }
    __builtin_amdgcn_s_barrier();
    asm volatile("" ::: "memory");
    consume(3);
    epiC(7);

    // row flush (C/D layout: col=n16, row=q*4+r)
#pragma unroll
    for (int rt = 0; rt < 2; ++rt)
#pragma unroll
        for (int r = 0; r < 4; ++r) {
            float s = rs[rt][r];
            s += __shfl_xor(s, 1, 64);
            s += __shfl_xor(s, 2, 64);
            s += __shfl_xor(s, 4, 64);
            s += __shfl_xor(s, 8, 64);
            if (n16 == 0) atomicAdd(&S[rowW + (rt << 4) + (q << 2) + r], s);
        }

    // off-diag only: cross-wave col reduction, ONE atomic per column. vmcnt is fully
    // drained above, so __syncthreads is safe here (also publishes colpart writes).
    if (!diag) {
        __syncthreads();
        if (tid < 256) {
            float s = 0.f;
#pragma unroll
            for (int w = 0; w < 8; ++w) s += colpart[w][tid];
            atomicAdd(&S[colTile + tid], s);
        }
    }
}

// ---------------- kernel 3: loss = mean( log(S_i - e^{sim_ii}) - sim_{i,target} ) -------
__global__ void __launch_bounds__(256) finish_kernel(
    const unsigned short* __restrict__ zn, const float* __restrict__ S,
    float* __restrict__ out)
{
    __shared__ float vals[16];
    const int tid = threadIdx.x, lane = tid & 63, wave = tid >> 6;
    const int q = lane >> 4, n16 = lane & 15;
    const int rib = (wave << 2) + q;                // 0..15 rows per block
    const int row = (blockIdx.x << 4) + rib;        // 512 blocks * 16 rows
    const int tar = (row + 4096) & 8191;

    float drr = 0.f, drt = 0.f;
#pragma unroll
    for (int i = 0; i < 4; ++i) {
        int k = (i << 6) + (n16 << 2);
        uint2 ur = *(const uint2*)(zn + (row << 8) + k);
        uint2 ut = *(const uint2*)(zn + (tar << 8) + k);
        float a0 = __uint_as_float(ur.x << 16),  a1 = __uint_as_float(ur.x & 0xFFFF0000u);
        float a2 = __uint_as_float(ur.y << 16),  a3 = __uint_as_float(ur.y & 0xFFFF0000u);
        float b0 = __uint_as_float(ut.x << 16),  b1 = __uint_as_float(ut.x & 0xFFFF0000u);
        float b2 = __uint_as_float(ut.y << 16),  b3 = __uint_as_float(ut.y & 0xFFFF0000u);
        drr += a0 * a0 + a1 * a1 + a2 * a2 + a3 * a3;
        drt += a0 * b0 + a1 * b1 + a2 * b2 + a3 * b3;
    }
#pragma unroll
    for (int m = 1; m <= 8; m <<= 1) {
        drr += __shfl_xor(drr, m, 64);
        drt += __shfl_xor(drt, m, 64);
    }
    if (n16 == 0) {
        float Sv = S[row] - __builtin_amdgcn_exp2f(drr * TWO_LOG2E);  // remove diagonal
        vals[rib] = 0.693147180559945f * __builtin_amdgcn_logf(Sv) - 2.0f * drt;
    }
    __syncthreads();
    if (tid == 0) {
        float s = 0.f;
#pragma unroll
        for (int i = 0; i < 16; ++i) s += vals[i];
        atomicAdd(out, s * (1.0f / 8192.0f));
    }
}

extern "C" void kernel_launch(void* const* d_in, const int* in_sizes, int n_in,
                              void* d_out, int out_size, void* d_ws, size_t ws_size,
                              hipStream_t stream)
{
    const float* z1 = (const float*)d_in[0];
    const float* z2 = (const float*)d_in[1];
    unsigned short* zn = (unsigned short*)d_ws;                              // 4 MB
    float* S = (float*)((char*)d_ws + 8192 * 256 * sizeof(unsigned short));  // 32 KB
    float* out = (float*)d_out;

    normalize_kernel<<<2048, 256, 0, stream>>>(z1, z2, zn, S, out);
    simexp_kernel<<<528, 512, 0, stream>>>(zn, S);
    finish_kernel<<<512, 256, 0, stream>>>(zn, S, out);
}